// Round 13
// baseline (279.899 us; speedup 1.0000x reference)
//
#include <hip/hip_runtime.h>

#define HH 383
#define WW 383
#define CINC 64
#define COUTC 128
#define HO 191
#define WO 191
#define MIDN (4L * HO * WO * COUTC)   // 18,690,048 elements
#define NIDX (4 * HH * WW)            // 586,756 pixels

typedef __attribute__((ext_vector_type(8))) short short8;
typedef __attribute__((ext_vector_type(8))) unsigned short ushort8;
typedef __attribute__((ext_vector_type(4))) float f32x4;

static __device__ inline unsigned short f2bf(float f) {
    unsigned u = __float_as_uint(f);
    unsigned r = (u + 0x7FFFu + ((u >> 16) & 1u)) >> 16;
    return (unsigned short)r;
}

// ---------------- prep: pack W1/W2 frags, feats->bf16 compact, zero row, counters, idx=-1 ----------
__global__ void prep(const float* __restrict__ feats,
                     const float* __restrict__ W1, const float* __restrict__ W2,
                     unsigned short* __restrict__ featsB,
                     unsigned short* __restrict__ W1p, unsigned short* __restrict__ W2p,
                     unsigned short* __restrict__ zrow, int* __restrict__ cnt,
                     int* __restrict__ idx, int npts) {
    int t = blockIdx.x * blockDim.x + threadIdx.x;
    int N = gridDim.x * blockDim.x;
    if (t < 73728) {
        int j  = t & 7;
        int l  = (t >> 3) & 63;
        int ng = (t >> 9) & 7;
        int tk = t >> 12;
        int tap = tk >> 1, kc = tk & 1;
        int ci = kc * 32 + (l >> 4) * 8 + j;
        int co = ng * 16 + (l & 15);
        W1p[t] = f2bf(W1[(tap * 64 + ci) * 128 + co]);
        int ng2  = (t >> 9) & 3;
        int kc2  = (t >> 11) & 3;
        int tap2 = t >> 13;
        int m = kc2 * 32 + (l >> 4) * 8 + j;
        int c = ng2 * 16 + (l & 15);
        W2p[t] = f2bf(W2[(tap2 * 128 + m) * 64 + c]);
    }
    if (t < 128) zrow[t] = 0;
    if (t < 4) cnt[t] = 0;
    for (int i = t; i < NIDX; i += N) idx[i] = -1;
    if (t < (npts + 1) * 8) {
        int p = t >> 3, q = t & 7;
        ushort8 v = {0, 0, 0, 0, 0, 0, 0, 0};
        if (p < npts) {
            const float4* f4 = (const float4*)(feats + (long)p * 64 + q * 8);
            float4 a = f4[0], b = f4[1];
            v[0] = f2bf(a.x); v[1] = f2bf(a.y); v[2] = f2bf(a.z); v[3] = f2bf(a.w);
            v[4] = f2bf(b.x); v[5] = f2bf(b.y); v[6] = f2bf(b.z); v[7] = f2bf(b.w);
        }
        *(ushort8*)&featsB[(long)p * 64 + q * 8] = v;
    }
}

// ---------------- classify: parity groups (wave-aggregated atomics) + pixel->point map ----------------
__global__ void classify(const int* __restrict__ coors, int npts,
                         int* __restrict__ grp, int* __restrict__ cnt,
                         int* __restrict__ idx) {
    int t = blockIdx.x * blockDim.x + threadIdx.x;
    int lane = threadIdx.x & 63;
    int g = -1;
    if (t < npts) {
        int b = coors[3 * t], y = coors[3 * t + 1], x = coors[3 * t + 2];
        g = (y & 1) * 2 + (x & 1);
        idx[(b * HH + y) * WW + x] = t;
    }
    #pragma unroll
    for (int gg = 0; gg < 4; ++gg) {
        unsigned long long mask = __ballot(g == gg);
        if (!mask) continue;
        int leader = __ffsll((long long)mask) - 1;
        int base = 0;
        if (lane == leader) base = atomicAdd(&cnt[gg], __popcll(mask));
        base = __shfl(base, leader);
        if (g == gg) {
            int rank = __popcll(mask & ((1ULL << lane) - 1ULL));
            grp[gg * npts + base + rank] = t;
        }
    }
}

// ---------------- conv1: 3x3 stride-2 VALID, bf16 MFMA, 64j-tile ----------------
// DIAGNOSTIC x4: blockIdx.z in [0,16): b = z&3, rep = z>>2; rep>0 writes identical data to mid2.
__global__ __launch_bounds__(256, 3) void conv1_mfma(const unsigned short* __restrict__ featsB,
                                                     const int* __restrict__ idxm,
                                                     const unsigned short* __restrict__ W1p,
                                                     unsigned short* __restrict__ mid0,
                                                     unsigned short* __restrict__ mid2,
                                                     int npts) {
    __shared__ unsigned short lds[3 * 132 * 64];  // 50,688 B
    __shared__ int ids[400];
    const int j0 = blockIdx.x * 64;
    const int i  = blockIdx.y;
    const int bz = blockIdx.z;
    const int b  = bz & 3;
    unsigned short* __restrict__ mid = (bz >> 2) ? mid2 : mid0;
    const int tid = threadIdx.x;
    const int w = tid >> 6, l = tid & 63;

    for (int t = tid; t < 396; t += 256) {
        int r = t / 132, xx = t - r * 132;
        int gx = 2 * j0 + xx;
        int id = npts;
        if (gx < WW) {
            int v = idxm[(b * HH + 2 * i + r) * WW + gx];
            if (v >= 0) id = v;
        }
        ids[t] = id;
    }
    __syncthreads();

    for (int t = tid; t < 3168; t += 256) {
        int pix = t >> 3, c8 = t & 7;
        int r = pix / 132, xx = pix - r * 132;
        ushort8 v = *(const ushort8*)&featsB[(long)ids[pix] * 64 + c8 * 8];
        int sidx = (r * 132 + xx) * 64 + ((c8 ^ ((xx >> 1) & 7)) << 3);
        *(ushort8*)&lds[sidx] = v;
    }
    __syncthreads();

    const int pj0 = l & 15;
    const int hi8 = (l >> 4) * 8;
    f32x4 zf = {0.f, 0.f, 0.f, 0.f};
    f32x4 acc[4][2];
    #pragma unroll
    for (int mt = 0; mt < 4; ++mt) { acc[mt][0] = zf; acc[mt][1] = zf; }

    for (int ky = 0; ky < 3; ++ky) {
        for (int kx = 0; kx < 3; ++kx) {
            const int tap = ky * 3 + kx;
            #pragma unroll
            for (int kc = 0; kc < 2; ++kc) {
                int fo = (((tap * 2 + kc) * 8 + 2 * w) << 9) + l * 8;
                short8 b0 = *(const short8*)&W1p[fo];
                short8 b1 = *(const short8*)&W1p[fo + 512];
                #pragma unroll
                for (int mt = 0; mt < 4; ++mt) {
                    int xx = 2 * (pj0 + mt * 16) + kx;
                    int idx2 = ((ky * 132 + xx) * 64 + kc * 32 + hi8) ^ (((xx >> 1) & 7) << 3);
                    short8 a = *(const short8*)&lds[idx2];
                    acc[mt][0] = __builtin_amdgcn_mfma_f32_16x16x32_bf16(a, b0, acc[mt][0], 0, 0, 0);
                    acc[mt][1] = __builtin_amdgcn_mfma_f32_16x16x32_bf16(a, b1, acc[mt][1], 0, 0, 0);
                }
            }
        }
    }

    const int n0 = 32 * w + (l & 15);
    const int rowbase = (l >> 4) * 4;
    #pragma unroll
    for (int mt = 0; mt < 4; ++mt) {
        #pragma unroll
        for (int reg = 0; reg < 4; ++reg) {
            int j = j0 + mt * 16 + rowbase + reg;
            if (j < WO) {
                long base = (((long)b * HO + i) * WO + j) * COUTC;
                mid[base + n0]      = f2bf(acc[mt][0][reg]);
                mid[base + n0 + 16] = f2bf(acc[mt][1][reg]);
            }
        }
    }
}

// ---------------- conv2: parity-grouped masked deconv via bf16 MFMA gather-GEMM ----------------
__global__ __launch_bounds__(256, 4) void conv2_mfma(const unsigned short* __restrict__ mid,
                                                     const unsigned short* __restrict__ W2p,
                                                     const int* __restrict__ coors,
                                                     const int* __restrict__ grp,
                                                     const int* __restrict__ cnt,
                                                     float* __restrict__ res, int npts) {
    __shared__ int meta[128 * 4];

    const int g  = blockIdx.y;
    const int n  = cnt[g];
    const int p0 = blockIdx.x * 128;
    if (p0 >= n) return;
    const int gy = g >> 1, gx = g & 1;
    const int tid = threadIdx.x, l = tid & 63, w = tid >> 6;

    if (tid < 128) {
        int pp = p0 + tid;
        if (pp < n) {
            int t = grp[g * npts + pp];
            meta[tid * 4 + 0] = coors[3 * t + 0];
            meta[tid * 4 + 1] = coors[3 * t + 1];
            meta[tid * 4 + 2] = coors[3 * t + 2];
            meta[tid * 4 + 3] = t;
        } else {
            meta[tid * 4 + 1] = -1;
        }
    }
    __syncthreads();

    const int pbase = w * 32;
    const int hi8 = (l >> 4) * 8;
    int bA[2], yA[2], xA[2];
    #pragma unroll
    for (int mt = 0; mt < 2; ++mt) {
        int pA = pbase + mt * 16 + (l & 15);
        bA[mt] = meta[pA * 4 + 0];
        yA[mt] = meta[pA * 4 + 1];
        xA[mt] = meta[pA * 4 + 2];
    }

    f32x4 zf = {0.f, 0.f, 0.f, 0.f};
    f32x4 acc[2][4];
    #pragma unroll
    for (int mt = 0; mt < 2; ++mt)
        #pragma unroll
        for (int ng = 0; ng < 4; ++ng) acc[mt][ng] = zf;

    const int nsy = gy ? 1 : 2, nsx = gx ? 1 : 2;
    for (int sy = 0; sy < nsy; ++sy) {
        const int ky = gy ? 1 : sy * 2;
        for (int sx = 0; sx < nsx; ++sx) {
            const int kx = gx ? 1 : sx * 2;
            const int tap = ky * 3 + kx;
            long off[2];
            #pragma unroll
            for (int mt = 0; mt < 2; ++mt) {
                int i = gy ? (yA[mt] >> 1) : ((yA[mt] >> 1) - 1 + sy);
                int j = gx ? (xA[mt] >> 1) : ((xA[mt] >> 1) - 1 + sx);
                bool ok = (yA[mt] >= 0) && (unsigned)i < (unsigned)HO && (unsigned)j < (unsigned)WO;
                off[mt] = ok ? ((long)(bA[mt] * HO + i) * WO + j) * COUTC : MIDN;
            }

            #pragma unroll
            for (int kc = 0; kc < 4; ++kc) {
                short8 a0 = *(const short8*)&mid[off[0] + kc * 32 + hi8];
                short8 a1 = *(const short8*)&mid[off[1] + kc * 32 + hi8];
                const unsigned short* wp = &W2p[((tap * 4 + kc) * 4) * 512 + l * 8];
                short8 b0 = *(const short8*)&wp[0];
                short8 b1 = *(const short8*)&wp[512];
                short8 b2 = *(const short8*)&wp[1024];
                short8 b3 = *(const short8*)&wp[1536];
                acc[0][0] = __builtin_amdgcn_mfma_f32_16x16x32_bf16(a0, b0, acc[0][0], 0, 0, 0);
                acc[0][1] = __builtin_amdgcn_mfma_f32_16x16x32_bf16(a0, b1, acc[0][1], 0, 0, 0);
                acc[0][2] = __builtin_amdgcn_mfma_f32_16x16x32_bf16(a0, b2, acc[0][2], 0, 0, 0);
                acc[0][3] = __builtin_amdgcn_mfma_f32_16x16x32_bf16(a0, b3, acc[0][3], 0, 0, 0);
                acc[1][0] = __builtin_amdgcn_mfma_f32_16x16x32_bf16(a1, b0, acc[1][0], 0, 0, 0);
                acc[1][1] = __builtin_amdgcn_mfma_f32_16x16x32_bf16(a1, b1, acc[1][1], 0, 0, 0);
                acc[1][2] = __builtin_amdgcn_mfma_f32_16x16x32_bf16(a1, b2, acc[1][2], 0, 0, 0);
                acc[1][3] = __builtin_amdgcn_mfma_f32_16x16x32_bf16(a1, b3, acc[1][3], 0, 0, 0);
            }
        }
    }

    #pragma unroll
    for (int mt = 0; mt < 2; ++mt) {
        #pragma unroll
        for (int reg = 0; reg < 4; ++reg) {
            int pl = pbase + mt * 16 + (l >> 4) * 4 + reg;
            if (meta[pl * 4 + 1] >= 0) {
                int pt = meta[pl * 4 + 3];
                float* rp = &res[(long)pt * 64 + (l & 15)];
                #pragma unroll
                for (int ng = 0; ng < 4; ++ng) rp[ng * 16] = acc[mt][ng][reg];
            }
        }
    }
}

// ---------------- expand: compact res + idx map -> dense NCHW output (coalesced) ----------------
__global__ __launch_bounds__(256) void expand(const float4* __restrict__ res4,
                                              const int* __restrict__ idx,
                                              float* __restrict__ out) {
    const int y = blockIdx.x, b = blockIdx.y;
    const int tid = threadIdx.x;
    const long plane = (long)HH * WW;
    const int rbase = (b * HH + y) * WW;

    #pragma unroll
    for (int half = 0; half < 2; ++half) {
        int x = half * 256 + tid;
        if (x < WW) {
            int id = idx[rbase + x];
            long obase = (long)b * 64 * plane + (long)y * WW + x;
            #pragma unroll 4
            for (int c4 = 0; c4 < 16; ++c4) {
                float4 v = make_float4(0.f, 0.f, 0.f, 0.f);
                if (id >= 0) v = res4[(long)id * 16 + c4];
                out[obase + (c4 * 4 + 0) * plane] = v.x;
                out[obase + (c4 * 4 + 1) * plane] = v.y;
                out[obase + (c4 * 4 + 2) * plane] = v.z;
                out[obase + (c4 * 4 + 3) * plane] = v.w;
            }
        }
    }
}

extern "C" void kernel_launch(void* const* d_in, const int* in_sizes, int n_in,
                              void* d_out, int out_size, void* d_ws, size_t ws_size,
                              hipStream_t stream) {
    const float* feats = (const float*)d_in[0];
    const int* coors = (const int*)d_in[1];
    const float* W1 = (const float*)d_in[3];
    const float* W2 = (const float*)d_in[4];
    float* out = (float*)d_out;
    int npts = in_sizes[1] / 3;

    char* wsb = (char*)d_ws;
    unsigned short* midB  = (unsigned short*)wsb;
    unsigned short* zrowB = midB + MIDN;
    unsigned short* W1p   = zrowB + 128;
    unsigned short* W2p   = W1p + 73728;
    int* cnt = (int*)(W2p + 73728);
    int* grp = cnt + 4;
    int* idx = grp + 4 * npts;
    float* res = (float*)(idx + NIDX);
    unsigned short* featsB = (unsigned short*)(res + (size_t)npts * 64);
    unsigned short* midB2  = featsB + (size_t)(npts + 1) * 64;  // dead diagnostic scratch

    // 1) fused prep
    int pthreads = (npts + 1) * 8;
    prep<<<(pthreads + 255) / 256, 256, 0, stream>>>(feats, W1, W2, featsB, W1p, W2p,
                                                     zrowB, cnt, idx, npts);

    // 2) classify
    classify<<<(npts + 255) / 256, 256, 0, stream>>>(coors, npts, grp, cnt, idx);

    // 3) conv1 (DIAGNOSTIC 4x via rep dimension)
    conv1_mfma<<<dim3(3, HO, 16), 256, 0, stream>>>(featsB, idx, W1p, midB, midB2, npts);

    // 4) conv2
    int pblocks = (npts + 127) / 128;
    conv2_mfma<<<dim3(pblocks, 4), 256, 0, stream>>>(midB, W2p, coors, grp, cnt, res, npts);

    // 5) expand
    expand<<<dim3(HH, 4), 256, 0, stream>>>((const float4*)res, idx, out);
}

// Round 14
// 211.514 us; speedup vs baseline: 1.3233x; 1.3233x over previous
//
#include <hip/hip_runtime.h>

#define HH 383
#define WW 383
#define CINC 64
#define COUTC 128
#define HO 191
#define WO 191
#define MIDN (4L * HO * WO * COUTC)   // 18,690,048 elements
#define NIDX (4 * HH * WW)            // 586,756 pixels

typedef __attribute__((ext_vector_type(8))) short short8;
typedef __attribute__((ext_vector_type(8))) unsigned short ushort8;
typedef __attribute__((ext_vector_type(4))) float f32x4;

static __device__ inline unsigned short f2bf(float f) {
    unsigned u = __float_as_uint(f);
    unsigned r = (u + 0x7FFFu + ((u >> 16) & 1u)) >> 16;
    return (unsigned short)r;
}

// ---------------- prep: pack W1/W2 frags, feats->bf16 compact, zero row, counters, idx=-1 ----------
__global__ void prep(const float* __restrict__ feats,
                     const float* __restrict__ W1, const float* __restrict__ W2,
                     unsigned short* __restrict__ featsB,
                     unsigned short* __restrict__ W1p, unsigned short* __restrict__ W2p,
                     unsigned short* __restrict__ zrow, int* __restrict__ cnt,
                     int* __restrict__ idx, int npts) {
    int t = blockIdx.x * blockDim.x + threadIdx.x;
    int N = gridDim.x * blockDim.x;
    if (t < 73728) {
        int j  = t & 7;
        int l  = (t >> 3) & 63;
        int ng = (t >> 9) & 7;
        int tk = t >> 12;
        int tap = tk >> 1, kc = tk & 1;
        int ci = kc * 32 + (l >> 4) * 8 + j;
        int co = ng * 16 + (l & 15);
        W1p[t] = f2bf(W1[(tap * 64 + ci) * 128 + co]);
        int ng2  = (t >> 9) & 3;
        int kc2  = (t >> 11) & 3;
        int tap2 = t >> 13;
        int m = kc2 * 32 + (l >> 4) * 8 + j;
        int c = ng2 * 16 + (l & 15);
        W2p[t] = f2bf(W2[(tap2 * 128 + m) * 64 + c]);
    }
    if (t < 128) zrow[t] = 0;
    if (t < 4) cnt[t] = 0;
    for (int i = t; i < NIDX; i += N) idx[i] = -1;
    if (t < (npts + 1) * 8) {
        int p = t >> 3, q = t & 7;
        ushort8 v = {0, 0, 0, 0, 0, 0, 0, 0};
        if (p < npts) {
            const float4* f4 = (const float4*)(feats + (long)p * 64 + q * 8);
            float4 a = f4[0], b = f4[1];
            v[0] = f2bf(a.x); v[1] = f2bf(a.y); v[2] = f2bf(a.z); v[3] = f2bf(a.w);
            v[4] = f2bf(b.x); v[5] = f2bf(b.y); v[6] = f2bf(b.z); v[7] = f2bf(b.w);
        }
        *(ushort8*)&featsB[(long)p * 64 + q * 8] = v;
    }
}

// ---------------- classify: parity groups (wave-aggregated atomics) + pixel->point map ----------------
__global__ void classify(const int* __restrict__ coors, int npts,
                         int* __restrict__ grp, int* __restrict__ cnt,
                         int* __restrict__ idx) {
    int t = blockIdx.x * blockDim.x + threadIdx.x;
    int lane = threadIdx.x & 63;
    int g = -1;
    if (t < npts) {
        int b = coors[3 * t], y = coors[3 * t + 1], x = coors[3 * t + 2];
        g = (y & 1) * 2 + (x & 1);
        idx[(b * HH + y) * WW + x] = t;
    }
    #pragma unroll
    for (int gg = 0; gg < 4; ++gg) {
        unsigned long long mask = __ballot(g == gg);
        if (!mask) continue;
        int leader = __ffsll((long long)mask) - 1;
        int base = 0;
        if (lane == leader) base = atomicAdd(&cnt[gg], __popcll(mask));
        base = __shfl(base, leader);
        if (g == gg) {
            int rank = __popcll(mask & ((1ULL << lane) - 1ULL));
            grp[gg * npts + base + rank] = t;
        }
    }
}

// ---------------- conv1: 3x3 stride-2 VALID, bf16 MFMA, 64j-tile, 8 waves/block ----------------
// block: 512 thr = 8 waves over 64 j x 128 co. wave w: co quarter (w&3)*32, j half (w>>2)*32.
// 3 blocks/CU (52 KB LDS) -> 24 waves/CU occupancy.
__global__ __launch_bounds__(512, 6) void conv1_mfma(const unsigned short* __restrict__ featsB,
                                                     const int* __restrict__ idxm,
                                                     const unsigned short* __restrict__ W1p,
                                                     unsigned short* __restrict__ mid, int npts) {
    __shared__ unsigned short lds[3 * 132 * 64];  // 50,688 B
    __shared__ int ids[400];
    const int j0 = blockIdx.x * 64;
    const int i  = blockIdx.y;
    const int b  = blockIdx.z;
    const int tid = threadIdx.x;
    const int w = tid >> 6, l = tid & 63;
    const int cq = w & 3;        // co quarter -> ng pair {2cq, 2cq+1}
    const int jh = w >> 2;       // j half -> mt' = jh*2 + mt

    // phase A: one idx lookup per pixel (rows 2i..2i+2, x = 2*j0 .. 2*j0+128)
    if (tid < 396) {
        int r = tid / 132, xx = tid - r * 132;
        int gx = 2 * j0 + xx;
        int id = npts;
        if (gx < WW) {
            int v = idxm[(b * HH + 2 * i + r) * WW + gx];
            if (v >= 0) id = v;
        }
        ids[tid] = id;
    }
    __syncthreads();

    // phase B: gather 16B slices; 8 consecutive lanes fetch one full 128B row
    for (int t = tid; t < 3168; t += 512) {
        int pix = t >> 3, c8 = t & 7;
        int r = pix / 132, xx = pix - r * 132;
        ushort8 v = *(const ushort8*)&featsB[(long)ids[pix] * 64 + c8 * 8];
        int sidx = (r * 132 + xx) * 64 + ((c8 ^ ((xx >> 1) & 7)) << 3);
        *(ushort8*)&lds[sidx] = v;
    }
    __syncthreads();

    const int pj0 = l & 15;
    const int hi8 = (l >> 4) * 8;
    f32x4 zf = {0.f, 0.f, 0.f, 0.f};
    f32x4 acc[2][2] = {{zf, zf}, {zf, zf}};

    for (int ky = 0; ky < 3; ++ky) {
        for (int kx = 0; kx < 3; ++kx) {
            const int tap = ky * 3 + kx;
            #pragma unroll
            for (int kc = 0; kc < 2; ++kc) {
                int fo = (((tap * 2 + kc) * 8 + 2 * cq) << 9) + l * 8;
                short8 b0 = *(const short8*)&W1p[fo];
                short8 b1 = *(const short8*)&W1p[fo + 512];
                #pragma unroll
                for (int mt = 0; mt < 2; ++mt) {
                    int xx = 2 * (pj0 + (jh * 2 + mt) * 16) + kx;
                    int idx2 = ((ky * 132 + xx) * 64 + kc * 32 + hi8) ^ (((xx >> 1) & 7) << 3);
                    short8 a = *(const short8*)&lds[idx2];
                    acc[mt][0] = __builtin_amdgcn_mfma_f32_16x16x32_bf16(a, b0, acc[mt][0], 0, 0, 0);
                    acc[mt][1] = __builtin_amdgcn_mfma_f32_16x16x32_bf16(a, b1, acc[mt][1], 0, 0, 0);
                }
            }
        }
    }

    // epilogue: D col = l&15 -> co, row = (l>>4)*4+reg -> j (m89-verified layout)
    const int n0 = 32 * cq + (l & 15);
    const int rowbase = (l >> 4) * 4;
    #pragma unroll
    for (int mt = 0; mt < 2; ++mt) {
        #pragma unroll
        for (int reg = 0; reg < 4; ++reg) {
            int j = j0 + (jh * 2 + mt) * 16 + rowbase + reg;
            if (j < WO) {
                long base = (((long)b * HO + i) * WO + j) * COUTC;
                mid[base + n0]      = f2bf(acc[mt][0][reg]);
                mid[base + n0 + 16] = f2bf(acc[mt][1][reg]);
            }
        }
    }
}

// ---------------- conv2: parity-grouped masked deconv via bf16 MFMA gather-GEMM ----------------
__global__ __launch_bounds__(256, 4) void conv2_mfma(const unsigned short* __restrict__ mid,
                                                     const unsigned short* __restrict__ W2p,
                                                     const int* __restrict__ coors,
                                                     const int* __restrict__ grp,
                                                     const int* __restrict__ cnt,
                                                     float* __restrict__ res, int npts) {
    __shared__ int meta[128 * 4];

    const int g  = blockIdx.y;
    const int n  = cnt[g];
    const int p0 = blockIdx.x * 128;
    if (p0 >= n) return;
    const int gy = g >> 1, gx = g & 1;
    const int tid = threadIdx.x, l = tid & 63, w = tid >> 6;

    if (tid < 128) {
        int pp = p0 + tid;
        if (pp < n) {
            int t = grp[g * npts + pp];
            meta[tid * 4 + 0] = coors[3 * t + 0];
            meta[tid * 4 + 1] = coors[3 * t + 1];
            meta[tid * 4 + 2] = coors[3 * t + 2];
            meta[tid * 4 + 3] = t;
        } else {
            meta[tid * 4 + 1] = -1;
        }
    }
    __syncthreads();

    const int pbase = w * 32;
    const int hi8 = (l >> 4) * 8;
    int bA[2], yA[2], xA[2];
    #pragma unroll
    for (int mt = 0; mt < 2; ++mt) {
        int pA = pbase + mt * 16 + (l & 15);
        bA[mt] = meta[pA * 4 + 0];
        yA[mt] = meta[pA * 4 + 1];
        xA[mt] = meta[pA * 4 + 2];
    }

    f32x4 zf = {0.f, 0.f, 0.f, 0.f};
    f32x4 acc[2][4];
    #pragma unroll
    for (int mt = 0; mt < 2; ++mt)
        #pragma unroll
        for (int ng = 0; ng < 4; ++ng) acc[mt][ng] = zf;

    const int nsy = gy ? 1 : 2, nsx = gx ? 1 : 2;
    for (int sy = 0; sy < nsy; ++sy) {
        const int ky = gy ? 1 : sy * 2;
        for (int sx = 0; sx < nsx; ++sx) {
            const int kx = gx ? 1 : sx * 2;
            const int tap = ky * 3 + kx;
            long off[2];
            #pragma unroll
            for (int mt = 0; mt < 2; ++mt) {
                int i = gy ? (yA[mt] >> 1) : ((yA[mt] >> 1) - 1 + sy);
                int j = gx ? (xA[mt] >> 1) : ((xA[mt] >> 1) - 1 + sx);
                bool ok = (yA[mt] >= 0) && (unsigned)i < (unsigned)HO && (unsigned)j < (unsigned)WO;
                off[mt] = ok ? ((long)(bA[mt] * HO + i) * WO + j) * COUTC : MIDN;
            }

            #pragma unroll
            for (int kc = 0; kc < 4; ++kc) {
                short8 a0 = *(const short8*)&mid[off[0] + kc * 32 + hi8];
                short8 a1 = *(const short8*)&mid[off[1] + kc * 32 + hi8];
                const unsigned short* wp = &W2p[((tap * 4 + kc) * 4) * 512 + l * 8];
                short8 b0 = *(const short8*)&wp[0];
                short8 b1 = *(const short8*)&wp[512];
                short8 b2 = *(const short8*)&wp[1024];
                short8 b3 = *(const short8*)&wp[1536];
                acc[0][0] = __builtin_amdgcn_mfma_f32_16x16x32_bf16(a0, b0, acc[0][0], 0, 0, 0);
                acc[0][1] = __builtin_amdgcn_mfma_f32_16x16x32_bf16(a0, b1, acc[0][1], 0, 0, 0);
                acc[0][2] = __builtin_amdgcn_mfma_f32_16x16x32_bf16(a0, b2, acc[0][2], 0, 0, 0);
                acc[0][3] = __builtin_amdgcn_mfma_f32_16x16x32_bf16(a0, b3, acc[0][3], 0, 0, 0);
                acc[1][0] = __builtin_amdgcn_mfma_f32_16x16x32_bf16(a1, b0, acc[1][0], 0, 0, 0);
                acc[1][1] = __builtin_amdgcn_mfma_f32_16x16x32_bf16(a1, b1, acc[1][1], 0, 0, 0);
                acc[1][2] = __builtin_amdgcn_mfma_f32_16x16x32_bf16(a1, b2, acc[1][2], 0, 0, 0);
                acc[1][3] = __builtin_amdgcn_mfma_f32_16x16x32_bf16(a1, b3, acc[1][3], 0, 0, 0);
            }
        }
    }

    #pragma unroll
    for (int mt = 0; mt < 2; ++mt) {
        #pragma unroll
        for (int reg = 0; reg < 4; ++reg) {
            int pl = pbase + mt * 16 + (l >> 4) * 4 + reg;
            if (meta[pl * 4 + 1] >= 0) {
                int pt = meta[pl * 4 + 3];
                float* rp = &res[(long)pt * 64 + (l & 15)];
                #pragma unroll
                for (int ng = 0; ng < 4; ++ng) rp[ng * 16] = acc[mt][ng][reg];
            }
        }
    }
}

// ---------------- expand: compact res + idx map -> dense NCHW output ----------------
// All 16 res4 loads issued before the 64 nontemporal stores (ILP over gather latency).
__global__ __launch_bounds__(256) void expand(const float4* __restrict__ res4,
                                              const int* __restrict__ idx,
                                              float* __restrict__ out) {
    const int y = blockIdx.x, b = blockIdx.y;
    const int tid = threadIdx.x;
    const long plane = (long)HH * WW;
    const int rbase = (b * HH + y) * WW;

    #pragma unroll
    for (int half = 0; half < 2; ++half) {
        int x = half * 256 + tid;
        if (x < WW) {
            int id = idx[rbase + x];
            long obase = (long)b * 64 * plane + (long)y * WW + x;
            float4 vv[16];
            const float4* rp = &res4[(long)(id >= 0 ? id : 0) * 16];
            #pragma unroll
            for (int c4 = 0; c4 < 16; ++c4)
                vv[c4] = (id >= 0) ? rp[c4] : make_float4(0.f, 0.f, 0.f, 0.f);
            #pragma unroll
            for (int c4 = 0; c4 < 16; ++c4) {
                __builtin_nontemporal_store(vv[c4].x, &out[obase + (c4 * 4 + 0) * plane]);
                __builtin_nontemporal_store(vv[c4].y, &out[obase + (c4 * 4 + 1) * plane]);
                __builtin_nontemporal_store(vv[c4].z, &out[obase + (c4 * 4 + 2) * plane]);
                __builtin_nontemporal_store(vv[c4].w, &out[obase + (c4 * 4 + 3) * plane]);
            }
        }
    }
}

extern "C" void kernel_launch(void* const* d_in, const int* in_sizes, int n_in,
                              void* d_out, int out_size, void* d_ws, size_t ws_size,
                              hipStream_t stream) {
    const float* feats = (const float*)d_in[0];
    const int* coors = (const int*)d_in[1];
    const float* W1 = (const float*)d_in[3];
    const float* W2 = (const float*)d_in[4];
    float* out = (float*)d_out;
    int npts = in_sizes[1] / 3;

    char* wsb = (char*)d_ws;
    unsigned short* midB  = (unsigned short*)wsb;
    unsigned short* zrowB = midB + MIDN;
    unsigned short* W1p   = zrowB + 128;
    unsigned short* W2p   = W1p + 73728;
    int* cnt = (int*)(W2p + 73728);
    int* grp = cnt + 4;
    int* idx = grp + 4 * npts;
    float* res = (float*)(idx + NIDX);
    unsigned short* featsB = (unsigned short*)(res + (size_t)npts * 64);

    // 1) fused prep
    int pthreads = (npts + 1) * 8;
    prep<<<(pthreads + 255) / 256, 256, 0, stream>>>(feats, W1, W2, featsB, W1p, W2p,
                                                     zrowB, cnt, idx, npts);

    // 2) classify: parity groups + pixel->point map
    classify<<<(npts + 255) / 256, 256, 0, stream>>>(coors, npts, grp, cnt, idx);

    // 3) conv1 via MFMA, 64j tile, 8 waves/block -> mid bf16
    conv1_mfma<<<dim3(3, HO, 4), 512, 0, stream>>>(featsB, idx, W1p, midB, npts);

    // 4) conv2 via MFMA -> compact res (indexed by original point id)
    int pblocks = (npts + 127) / 128;
    conv2_mfma<<<dim3(pblocks, 4), 256, 0, stream>>>(midB, W2p, coors, grp, cnt, res, npts);

    // 5) expand compact res to dense NCHW output (writes every element)
    expand<<<dim3(HH, 4), 256, 0, stream>>>((const float4*)res, idx, out);
}

// Round 15
// 181.392 us; speedup vs baseline: 1.5431x; 1.1661x over previous
//
#include <hip/hip_runtime.h>

#define HH 383
#define WW 383
#define CINC 64
#define COUTC 128
#define HO 191
#define WO 191
#define MIDN (4L * HO * WO * COUTC)   // 18,690,048 elements
#define NIDX (4 * HH * WW)            // 586,756 pixels

typedef __attribute__((ext_vector_type(8))) short short8;
typedef __attribute__((ext_vector_type(8))) unsigned short ushort8;
typedef __attribute__((ext_vector_type(4))) float f32x4;

static __device__ inline unsigned short f2bf(float f) {
    unsigned u = __float_as_uint(f);
    unsigned r = (u + 0x7FFFu + ((u >> 16) & 1u)) >> 16;
    return (unsigned short)r;
}

// ---------------- prep: pack W1/W2 frags, feats->bf16 compact, zero row, counters, idx=-1 ----------
__global__ void prep(const float* __restrict__ feats,
                     const float* __restrict__ W1, const float* __restrict__ W2,
                     unsigned short* __restrict__ featsB,
                     unsigned short* __restrict__ W1p, unsigned short* __restrict__ W2p,
                     unsigned short* __restrict__ zrow, int* __restrict__ cnt,
                     int* __restrict__ idx, int npts) {
    int t = blockIdx.x * blockDim.x + threadIdx.x;
    int N = gridDim.x * blockDim.x;
    if (t < 73728) {
        int j  = t & 7;
        int l  = (t >> 3) & 63;
        int ng = (t >> 9) & 7;
        int tk = t >> 12;
        int tap = tk >> 1, kc = tk & 1;
        int ci = kc * 32 + (l >> 4) * 8 + j;
        int co = ng * 16 + (l & 15);
        W1p[t] = f2bf(W1[(tap * 64 + ci) * 128 + co]);
        int ng2  = (t >> 9) & 3;
        int kc2  = (t >> 11) & 3;
        int tap2 = t >> 13;
        int m = kc2 * 32 + (l >> 4) * 8 + j;
        int c = ng2 * 16 + (l & 15);
        W2p[t] = f2bf(W2[(tap2 * 128 + m) * 64 + c]);
    }
    if (t < 128) zrow[t] = 0;
    if (t < 4) cnt[t] = 0;
    for (int i = t; i < NIDX; i += N) idx[i] = -1;
    if (t < (npts + 1) * 8) {
        int p = t >> 3, q = t & 7;
        ushort8 v = {0, 0, 0, 0, 0, 0, 0, 0};
        if (p < npts) {
            const float4* f4 = (const float4*)(feats + (long)p * 64 + q * 8);
            float4 a = f4[0], b = f4[1];
            v[0] = f2bf(a.x); v[1] = f2bf(a.y); v[2] = f2bf(a.z); v[3] = f2bf(a.w);
            v[4] = f2bf(b.x); v[5] = f2bf(b.y); v[6] = f2bf(b.z); v[7] = f2bf(b.w);
        }
        *(ushort8*)&featsB[(long)p * 64 + q * 8] = v;
    }
}

// ---------------- classify: parity groups (wave-aggregated atomics) + pixel->point map ----------------
__global__ void classify(const int* __restrict__ coors, int npts,
                         int* __restrict__ grp, int* __restrict__ cnt,
                         int* __restrict__ idx) {
    int t = blockIdx.x * blockDim.x + threadIdx.x;
    int lane = threadIdx.x & 63;
    int g = -1;
    if (t < npts) {
        int b = coors[3 * t], y = coors[3 * t + 1], x = coors[3 * t + 2];
        g = (y & 1) * 2 + (x & 1);
        idx[(b * HH + y) * WW + x] = t;
    }
    #pragma unroll
    for (int gg = 0; gg < 4; ++gg) {
        unsigned long long mask = __ballot(g == gg);
        if (!mask) continue;
        int leader = __ffsll((long long)mask) - 1;
        int base = 0;
        if (lane == leader) base = atomicAdd(&cnt[gg], __popcll(mask));
        base = __shfl(base, leader);
        if (g == gg) {
            int rank = __popcll(mask & ((1ULL << lane) - 1ULL));
            grp[gg * npts + base + rank] = t;
        }
    }
}

// ---------------- conv1: 3x3 stride-2 VALID, bf16 MFMA, 64j-tile, wave = 32j x 64co ----------------
// block: 256 thr = 4 waves over 64 j x 128 co. wave w: j-half jh=w>>1, co-half ch=w&1.
// Per (tap,kc): 2 A ds_reads feed 4 B-frags -> 8 MFMA (A-reads/block halved vs 64jx32co wave).
__global__ __launch_bounds__(256, 3) void conv1_mfma(const unsigned short* __restrict__ featsB,
                                                     const int* __restrict__ idxm,
                                                     const unsigned short* __restrict__ W1p,
                                                     unsigned short* __restrict__ mid, int npts) {
    __shared__ unsigned short lds[3 * 132 * 64];  // 50,688 B
    __shared__ int ids[400];
    const int j0 = blockIdx.x * 64;
    const int i  = blockIdx.y;
    const int b  = blockIdx.z;
    const int tid = threadIdx.x;
    const int w = tid >> 6, l = tid & 63;
    const int jh = w >> 1;   // j half
    const int ch = w & 1;    // co half -> ngAbs = ch*4 + ng

    // phase A: one idx lookup per pixel (rows 2i..2i+2, x = 2*j0 .. 2*j0+128)
    for (int t = tid; t < 396; t += 256) {
        int r = t / 132, xx = t - r * 132;
        int gx = 2 * j0 + xx;
        int id = npts;
        if (gx < WW) {
            int v = idxm[(b * HH + 2 * i + r) * WW + gx];
            if (v >= 0) id = v;
        }
        ids[t] = id;
    }
    __syncthreads();

    // phase B: gather 16B slices; 8 consecutive lanes fetch one full 128B row
    for (int t = tid; t < 3168; t += 256) {
        int pix = t >> 3, c8 = t & 7;
        int r = pix / 132, xx = pix - r * 132;
        ushort8 v = *(const ushort8*)&featsB[(long)ids[pix] * 64 + c8 * 8];
        int sidx = (r * 132 + xx) * 64 + ((c8 ^ ((xx >> 1) & 7)) << 3);
        *(ushort8*)&lds[sidx] = v;
    }
    __syncthreads();

    const int pj0 = l & 15;
    const int hi8 = (l >> 4) * 8;
    f32x4 zf = {0.f, 0.f, 0.f, 0.f};
    f32x4 acc[2][4];
    #pragma unroll
    for (int mt = 0; mt < 2; ++mt)
        #pragma unroll
        for (int ng = 0; ng < 4; ++ng) acc[mt][ng] = zf;

    for (int ky = 0; ky < 3; ++ky) {
        for (int kx = 0; kx < 3; ++kx) {
            const int tap = ky * 3 + kx;
            #pragma unroll
            for (int kc = 0; kc < 2; ++kc) {
                const unsigned short* wp = &W1p[(((tap * 2 + kc) * 8 + ch * 4) << 9) + l * 8];
                short8 b0 = *(const short8*)&wp[0];
                short8 b1 = *(const short8*)&wp[512];
                short8 b2 = *(const short8*)&wp[1024];
                short8 b3 = *(const short8*)&wp[1536];
                #pragma unroll
                for (int mt = 0; mt < 2; ++mt) {
                    int xx = 2 * (pj0 + (jh * 2 + mt) * 16) + kx;
                    int idx2 = ((ky * 132 + xx) * 64 + kc * 32 + hi8) ^ (((xx >> 1) & 7) << 3);
                    short8 a = *(const short8*)&lds[idx2];
                    acc[mt][0] = __builtin_amdgcn_mfma_f32_16x16x32_bf16(a, b0, acc[mt][0], 0, 0, 0);
                    acc[mt][1] = __builtin_amdgcn_mfma_f32_16x16x32_bf16(a, b1, acc[mt][1], 0, 0, 0);
                    acc[mt][2] = __builtin_amdgcn_mfma_f32_16x16x32_bf16(a, b2, acc[mt][2], 0, 0, 0);
                    acc[mt][3] = __builtin_amdgcn_mfma_f32_16x16x32_bf16(a, b3, acc[mt][3], 0, 0, 0);
                }
            }
        }
    }

    // epilogue: D col = l&15 -> co, row = (l>>4)*4+reg -> j (m89-verified layout)
    const int coBase = ch * 64 + (l & 15);
    const int rowbase = (l >> 4) * 4;
    #pragma unroll
    for (int mt = 0; mt < 2; ++mt) {
        #pragma unroll
        for (int reg = 0; reg < 4; ++reg) {
            int j = j0 + (jh * 2 + mt) * 16 + rowbase + reg;
            if (j < WO) {
                long base = (((long)b * HO + i) * WO + j) * COUTC + coBase;
                #pragma unroll
                for (int ng = 0; ng < 4; ++ng)
                    mid[base + ng * 16] = f2bf(acc[mt][ng][reg]);
            }
        }
    }
}

// ---------------- conv2: parity-grouped masked deconv via bf16 MFMA gather-GEMM ----------------
__global__ __launch_bounds__(256, 4) void conv2_mfma(const unsigned short* __restrict__ mid,
                                                     const unsigned short* __restrict__ W2p,
                                                     const int* __restrict__ coors,
                                                     const int* __restrict__ grp,
                                                     const int* __restrict__ cnt,
                                                     float* __restrict__ res, int npts) {
    __shared__ int meta[128 * 4];

    const int g  = blockIdx.y;
    const int n  = cnt[g];
    const int p0 = blockIdx.x * 128;
    if (p0 >= n) return;
    const int gy = g >> 1, gx = g & 1;
    const int tid = threadIdx.x, l = tid & 63, w = tid >> 6;

    if (tid < 128) {
        int pp = p0 + tid;
        if (pp < n) {
            int t = grp[g * npts + pp];
            meta[tid * 4 + 0] = coors[3 * t + 0];
            meta[tid * 4 + 1] = coors[3 * t + 1];
            meta[tid * 4 + 2] = coors[3 * t + 2];
            meta[tid * 4 + 3] = t;
        } else {
            meta[tid * 4 + 1] = -1;
        }
    }
    __syncthreads();

    const int pbase = w * 32;
    const int hi8 = (l >> 4) * 8;
    int bA[2], yA[2], xA[2];
    #pragma unroll
    for (int mt = 0; mt < 2; ++mt) {
        int pA = pbase + mt * 16 + (l & 15);
        bA[mt] = meta[pA * 4 + 0];
        yA[mt] = meta[pA * 4 + 1];
        xA[mt] = meta[pA * 4 + 2];
    }

    f32x4 zf = {0.f, 0.f, 0.f, 0.f};
    f32x4 acc[2][4];
    #pragma unroll
    for (int mt = 0; mt < 2; ++mt)
        #pragma unroll
        for (int ng = 0; ng < 4; ++ng) acc[mt][ng] = zf;

    const int nsy = gy ? 1 : 2, nsx = gx ? 1 : 2;
    for (int sy = 0; sy < nsy; ++sy) {
        const int ky = gy ? 1 : sy * 2;
        for (int sx = 0; sx < nsx; ++sx) {
            const int kx = gx ? 1 : sx * 2;
            const int tap = ky * 3 + kx;
            long off[2];
            #pragma unroll
            for (int mt = 0; mt < 2; ++mt) {
                int i = gy ? (yA[mt] >> 1) : ((yA[mt] >> 1) - 1 + sy);
                int j = gx ? (xA[mt] >> 1) : ((xA[mt] >> 1) - 1 + sx);
                bool ok = (yA[mt] >= 0) && (unsigned)i < (unsigned)HO && (unsigned)j < (unsigned)WO;
                off[mt] = ok ? ((long)(bA[mt] * HO + i) * WO + j) * COUTC : MIDN;
            }

            #pragma unroll
            for (int kc = 0; kc < 4; ++kc) {
                short8 a0 = *(const short8*)&mid[off[0] + kc * 32 + hi8];
                short8 a1 = *(const short8*)&mid[off[1] + kc * 32 + hi8];
                const unsigned short* wp = &W2p[((tap * 4 + kc) * 4) * 512 + l * 8];
                short8 b0 = *(const short8*)&wp[0];
                short8 b1 = *(const short8*)&wp[512];
                short8 b2 = *(const short8*)&wp[1024];
                short8 b3 = *(const short8*)&wp[1536];
                acc[0][0] = __builtin_amdgcn_mfma_f32_16x16x32_bf16(a0, b0, acc[0][0], 0, 0, 0);
                acc[0][1] = __builtin_amdgcn_mfma_f32_16x16x32_bf16(a0, b1, acc[0][1], 0, 0, 0);
                acc[0][2] = __builtin_amdgcn_mfma_f32_16x16x32_bf16(a0, b2, acc[0][2], 0, 0, 0);
                acc[0][3] = __builtin_amdgcn_mfma_f32_16x16x32_bf16(a0, b3, acc[0][3], 0, 0, 0);
                acc[1][0] = __builtin_amdgcn_mfma_f32_16x16x32_bf16(a1, b0, acc[1][0], 0, 0, 0);
                acc[1][1] = __builtin_amdgcn_mfma_f32_16x16x32_bf16(a1, b1, acc[1][1], 0, 0, 0);
                acc[1][2] = __builtin_amdgcn_mfma_f32_16x16x32_bf16(a1, b2, acc[1][2], 0, 0, 0);
                acc[1][3] = __builtin_amdgcn_mfma_f32_16x16x32_bf16(a1, b3, acc[1][3], 0, 0, 0);
            }
        }
    }

    #pragma unroll
    for (int mt = 0; mt < 2; ++mt) {
        #pragma unroll
        for (int reg = 0; reg < 4; ++reg) {
            int pl = pbase + mt * 16 + (l >> 4) * 4 + reg;
            if (meta[pl * 4 + 1] >= 0) {
                int pt = meta[pl * 4 + 3];
                float* rp = &res[(long)pt * 64 + (l & 15)];
                #pragma unroll
                for (int ng = 0; ng < 4; ++ng) rp[ng * 16] = acc[mt][ng][reg];
            }
        }
    }
}

// ---------------- expand: compact res + idx map -> dense NCHW output (coalesced) ----------------
__global__ __launch_bounds__(256) void expand(const float4* __restrict__ res4,
                                              const int* __restrict__ idx,
                                              float* __restrict__ out) {
    const int y = blockIdx.x, b = blockIdx.y;
    const int tid = threadIdx.x;
    const long plane = (long)HH * WW;
    const int rbase = (b * HH + y) * WW;

    #pragma unroll
    for (int half = 0; half < 2; ++half) {
        int x = half * 256 + tid;
        if (x < WW) {
            int id = idx[rbase + x];
            long obase = (long)b * 64 * plane + (long)y * WW + x;
            #pragma unroll 4
            for (int c4 = 0; c4 < 16; ++c4) {
                float4 v = make_float4(0.f, 0.f, 0.f, 0.f);
                if (id >= 0) v = res4[(long)id * 16 + c4];
                out[obase + (c4 * 4 + 0) * plane] = v.x;
                out[obase + (c4 * 4 + 1) * plane] = v.y;
                out[obase + (c4 * 4 + 2) * plane] = v.z;
                out[obase + (c4 * 4 + 3) * plane] = v.w;
            }
        }
    }
}

extern "C" void kernel_launch(void* const* d_in, const int* in_sizes, int n_in,
                              void* d_out, int out_size, void* d_ws, size_t ws_size,
                              hipStream_t stream) {
    const float* feats = (const float*)d_in[0];
    const int* coors = (const int*)d_in[1];
    const float* W1 = (const float*)d_in[3];
    const float* W2 = (const float*)d_in[4];
    float* out = (float*)d_out;
    int npts = in_sizes[1] / 3;

    char* wsb = (char*)d_ws;
    unsigned short* midB  = (unsigned short*)wsb;
    unsigned short* zrowB = midB + MIDN;
    unsigned short* W1p   = zrowB + 128;
    unsigned short* W2p   = W1p + 73728;
    int* cnt = (int*)(W2p + 73728);
    int* grp = cnt + 4;
    int* idx = grp + 4 * npts;
    float* res = (float*)(idx + NIDX);
    unsigned short* featsB = (unsigned short*)(res + (size_t)npts * 64);

    // 1) fused prep
    int pthreads = (npts + 1) * 8;
    prep<<<(pthreads + 255) / 256, 256, 0, stream>>>(feats, W1, W2, featsB, W1p, W2p,
                                                     zrowB, cnt, idx, npts);

    // 2) classify: parity groups + pixel->point map
    classify<<<(npts + 255) / 256, 256, 0, stream>>>(coors, npts, grp, cnt, idx);

    // 3) conv1 via MFMA, 64j tile, wave = 32j x 64co -> mid bf16
    conv1_mfma<<<dim3(3, HO, 4), 256, 0, stream>>>(featsB, idx, W1p, midB, npts);

    // 4) conv2 via MFMA -> compact res (indexed by original point id)
    int pblocks = (npts + 127) / 128;
    conv2_mfma<<<dim3(pblocks, 4), 256, 0, stream>>>(midB, W2p, coors, grp, cnt, res, npts);

    // 5) expand compact res to dense NCHW output (writes every element)
    expand<<<dim3(HH, 4), 256, 0, stream>>>((const float4*)res, idx, out);
}

// Round 16
// 110.442 us; speedup vs baseline: 2.5344x; 1.6424x over previous
//
#include <hip/hip_runtime.h>

#define HH 383
#define WW 383
#define CINC 64
#define COUTC 128
#define HO 191
#define WO 191
#define MIDN (4L * HO * WO * COUTC)   // 18,690,048 elements
#define NIDX (4 * HH * WW)            // 586,756 pixels

typedef __attribute__((ext_vector_type(8))) short short8;
typedef __attribute__((ext_vector_type(8))) unsigned short ushort8;
typedef __attribute__((ext_vector_type(4))) float f32x4;

static __device__ inline unsigned short f2bf(float f) {
    unsigned u = __float_as_uint(f);
    unsigned r = (u + 0x7FFFu + ((u >> 16) & 1u)) >> 16;
    return (unsigned short)r;
}

// ---------------- prep: pack W1/W2 frags, feats->bf16 compact, zero row, counters, idx=-1 ----------
__global__ void prep(const float* __restrict__ feats,
                     const float* __restrict__ W1, const float* __restrict__ W2,
                     unsigned short* __restrict__ featsB,
                     unsigned short* __restrict__ W1p, unsigned short* __restrict__ W2p,
                     unsigned short* __restrict__ zrow, int* __restrict__ cnt,
                     int* __restrict__ idx, int npts) {
    int t = blockIdx.x * blockDim.x + threadIdx.x;
    int N = gridDim.x * blockDim.x;
    if (t < 73728) {
        int j  = t & 7;
        int l  = (t >> 3) & 63;
        int ng = (t >> 9) & 7;
        int tk = t >> 12;
        int tap = tk >> 1, kc = tk & 1;
        int ci = kc * 32 + (l >> 4) * 8 + j;
        int co = ng * 16 + (l & 15);
        W1p[t] = f2bf(W1[(tap * 64 + ci) * 128 + co]);
        int ng2  = (t >> 9) & 3;
        int kc2  = (t >> 11) & 3;
        int tap2 = t >> 13;
        int m = kc2 * 32 + (l >> 4) * 8 + j;
        int c = ng2 * 16 + (l & 15);
        W2p[t] = f2bf(W2[(tap2 * 128 + m) * 64 + c]);
    }
    if (t < 128) zrow[t] = 0;
    if (t < 128) cnt[t] = 0;   // 4 counters at stride 32 ints (128 B) + padding
    for (int i = t; i < NIDX; i += N) idx[i] = -1;
    if (t < (npts + 1) * 8) {
        int p = t >> 3, q = t & 7;
        ushort8 v = {0, 0, 0, 0, 0, 0, 0, 0};
        if (p < npts) {
            const float4* f4 = (const float4*)(feats + (long)p * 64 + q * 8);
            float4 a = f4[0], b = f4[1];
            v[0] = f2bf(a.x); v[1] = f2bf(a.y); v[2] = f2bf(a.z); v[3] = f2bf(a.w);
            v[4] = f2bf(b.x); v[5] = f2bf(b.y); v[6] = f2bf(b.z); v[7] = f2bf(b.w);
        }
        *(ushort8*)&featsB[(long)p * 64 + q * 8] = v;
    }
}

// ---------------- classify: block-aggregated parity grouping + pixel->point map ----------------
// One atomicAdd per (block, group) on 128B-padded counters; slot = block_base + wave_prefix + rank.
__global__ __launch_bounds__(256) void classify(const int* __restrict__ coors, int npts,
                                                int* __restrict__ grp, int* __restrict__ cnt,
                                                int* __restrict__ idx) {
    __shared__ int wcnt[4][4];   // [wave][group] counts, then exclusive wave-prefix
    __shared__ int bbase[4];     // block's global base per group
    int t = blockIdx.x * blockDim.x + threadIdx.x;
    int lane = threadIdx.x & 63, w = threadIdx.x >> 6;
    int g = -1;
    if (t < npts) {
        int b = coors[3 * t], y = coors[3 * t + 1], x = coors[3 * t + 2];
        g = (y & 1) * 2 + (x & 1);
        idx[(b * HH + y) * WW + x] = t;
    }
    int myrank = 0;
    #pragma unroll
    for (int gg = 0; gg < 4; ++gg) {
        unsigned long long mask = __ballot(g == gg);
        if (lane == 0) wcnt[w][gg] = __popcll(mask);
        if (g == gg) myrank = __popcll(mask & ((1ULL << lane) - 1ULL));
    }
    __syncthreads();
    if (threadIdx.x < 4) {
        int gg = threadIdx.x;
        int s0 = wcnt[0][gg], s1 = wcnt[1][gg], s2 = wcnt[2][gg], s3 = wcnt[3][gg];
        int tot = s0 + s1 + s2 + s3;
        bbase[gg] = tot ? atomicAdd(&cnt[gg * 32], tot) : 0;
        wcnt[0][gg] = 0;
        wcnt[1][gg] = s0;
        wcnt[2][gg] = s0 + s1;
        wcnt[3][gg] = s0 + s1 + s2;
    }
    __syncthreads();
    if (g >= 0)
        grp[g * npts + bbase[g] + wcnt[w][g] + myrank] = t;
}

// ---------------- conv1: 3x3 stride-2 VALID, bf16 MFMA, 64j-tile (R12 version) ----------------
// block: 64 j x 128 co, 4 waves; wave w: co range [32w, 32w+32) (2 ng), ALL 64 j (4 m-tiles).
__global__ __launch_bounds__(256, 3) void conv1_mfma(const unsigned short* __restrict__ featsB,
                                                     const int* __restrict__ idxm,
                                                     const unsigned short* __restrict__ W1p,
                                                     unsigned short* __restrict__ mid, int npts) {
    __shared__ unsigned short lds[3 * 132 * 64];  // 50,688 B
    __shared__ int ids[400];
    const int j0 = blockIdx.x * 64;
    const int i  = blockIdx.y;
    const int b  = blockIdx.z;
    const int tid = threadIdx.x;
    const int w = tid >> 6, l = tid & 63;

    for (int t = tid; t < 396; t += 256) {
        int r = t / 132, xx = t - r * 132;
        int gx = 2 * j0 + xx;
        int id = npts;
        if (gx < WW) {
            int v = idxm[(b * HH + 2 * i + r) * WW + gx];
            if (v >= 0) id = v;
        }
        ids[t] = id;
    }
    __syncthreads();

    for (int t = tid; t < 3168; t += 256) {
        int pix = t >> 3, c8 = t & 7;
        int r = pix / 132, xx = pix - r * 132;
        ushort8 v = *(const ushort8*)&featsB[(long)ids[pix] * 64 + c8 * 8];
        int sidx = (r * 132 + xx) * 64 + ((c8 ^ ((xx >> 1) & 7)) << 3);
        *(ushort8*)&lds[sidx] = v;
    }
    __syncthreads();

    const int pj0 = l & 15;
    const int hi8 = (l >> 4) * 8;
    f32x4 zf = {0.f, 0.f, 0.f, 0.f};
    f32x4 acc[4][2];
    #pragma unroll
    for (int mt = 0; mt < 4; ++mt) { acc[mt][0] = zf; acc[mt][1] = zf; }

    for (int ky = 0; ky < 3; ++ky) {
        for (int kx = 0; kx < 3; ++kx) {
            const int tap = ky * 3 + kx;
            #pragma unroll
            for (int kc = 0; kc < 2; ++kc) {
                int fo = (((tap * 2 + kc) * 8 + 2 * w) << 9) + l * 8;
                short8 b0 = *(const short8*)&W1p[fo];
                short8 b1 = *(const short8*)&W1p[fo + 512];
                #pragma unroll
                for (int mt = 0; mt < 4; ++mt) {
                    int xx = 2 * (pj0 + mt * 16) + kx;
                    int idx2 = ((ky * 132 + xx) * 64 + kc * 32 + hi8) ^ (((xx >> 1) & 7) << 3);
                    short8 a = *(const short8*)&lds[idx2];
                    acc[mt][0] = __builtin_amdgcn_mfma_f32_16x16x32_bf16(a, b0, acc[mt][0], 0, 0, 0);
                    acc[mt][1] = __builtin_amdgcn_mfma_f32_16x16x32_bf16(a, b1, acc[mt][1], 0, 0, 0);
                }
            }
        }
    }

    const int n0 = 32 * w + (l & 15);
    const int rowbase = (l >> 4) * 4;
    #pragma unroll
    for (int mt = 0; mt < 4; ++mt) {
        #pragma unroll
        for (int reg = 0; reg < 4; ++reg) {
            int j = j0 + mt * 16 + rowbase + reg;
            if (j < WO) {
                long base = (((long)b * HO + i) * WO + j) * COUTC;
                mid[base + n0]      = f2bf(acc[mt][0][reg]);
                mid[base + n0 + 16] = f2bf(acc[mt][1][reg]);
            }
        }
    }
}

// ---------------- conv2: parity-grouped masked deconv via bf16 MFMA gather-GEMM ----------------
__global__ __launch_bounds__(256, 4) void conv2_mfma(const unsigned short* __restrict__ mid,
                                                     const unsigned short* __restrict__ W2p,
                                                     const int* __restrict__ coors,
                                                     const int* __restrict__ grp,
                                                     const int* __restrict__ cnt,
                                                     float* __restrict__ res, int npts) {
    __shared__ int meta[128 * 4];

    const int g  = blockIdx.y;
    const int n  = cnt[g * 32];
    const int p0 = blockIdx.x * 128;
    if (p0 >= n) return;
    const int gy = g >> 1, gx = g & 1;
    const int tid = threadIdx.x, l = tid & 63, w = tid >> 6;

    if (tid < 128) {
        int pp = p0 + tid;
        if (pp < n) {
            int t = grp[g * npts + pp];
            meta[tid * 4 + 0] = coors[3 * t + 0];
            meta[tid * 4 + 1] = coors[3 * t + 1];
            meta[tid * 4 + 2] = coors[3 * t + 2];
            meta[tid * 4 + 3] = t;
        } else {
            meta[tid * 4 + 1] = -1;
        }
    }
    __syncthreads();

    const int pbase = w * 32;
    const int hi8 = (l >> 4) * 8;
    int bA[2], yA[2], xA[2];
    #pragma unroll
    for (int mt = 0; mt < 2; ++mt) {
        int pA = pbase + mt * 16 + (l & 15);
        bA[mt] = meta[pA * 4 + 0];
        yA[mt] = meta[pA * 4 + 1];
        xA[mt] = meta[pA * 4 + 2];
    }

    f32x4 zf = {0.f, 0.f, 0.f, 0.f};
    f32x4 acc[2][4];
    #pragma unroll
    for (int mt = 0; mt < 2; ++mt)
        #pragma unroll
        for (int ng = 0; ng < 4; ++ng) acc[mt][ng] = zf;

    const int nsy = gy ? 1 : 2, nsx = gx ? 1 : 2;
    for (int sy = 0; sy < nsy; ++sy) {
        const int ky = gy ? 1 : sy * 2;
        for (int sx = 0; sx < nsx; ++sx) {
            const int kx = gx ? 1 : sx * 2;
            const int tap = ky * 3 + kx;
            long off[2];
            #pragma unroll
            for (int mt = 0; mt < 2; ++mt) {
                int i = gy ? (yA[mt] >> 1) : ((yA[mt] >> 1) - 1 + sy);
                int j = gx ? (xA[mt] >> 1) : ((xA[mt] >> 1) - 1 + sx);
                bool ok = (yA[mt] >= 0) && (unsigned)i < (unsigned)HO && (unsigned)j < (unsigned)WO;
                off[mt] = ok ? ((long)(bA[mt] * HO + i) * WO + j) * COUTC : MIDN;
            }

            #pragma unroll
            for (int kc = 0; kc < 4; ++kc) {
                short8 a0 = *(const short8*)&mid[off[0] + kc * 32 + hi8];
                short8 a1 = *(const short8*)&mid[off[1] + kc * 32 + hi8];
                const unsigned short* wp = &W2p[((tap * 4 + kc) * 4) * 512 + l * 8];
                short8 b0 = *(const short8*)&wp[0];
                short8 b1 = *(const short8*)&wp[512];
                short8 b2 = *(const short8*)&wp[1024];
                short8 b3 = *(const short8*)&wp[1536];
                acc[0][0] = __builtin_amdgcn_mfma_f32_16x16x32_bf16(a0, b0, acc[0][0], 0, 0, 0);
                acc[0][1] = __builtin_amdgcn_mfma_f32_16x16x32_bf16(a0, b1, acc[0][1], 0, 0, 0);
                acc[0][2] = __builtin_amdgcn_mfma_f32_16x16x32_bf16(a0, b2, acc[0][2], 0, 0, 0);
                acc[0][3] = __builtin_amdgcn_mfma_f32_16x16x32_bf16(a0, b3, acc[0][3], 0, 0, 0);
                acc[1][0] = __builtin_amdgcn_mfma_f32_16x16x32_bf16(a1, b0, acc[1][0], 0, 0, 0);
                acc[1][1] = __builtin_amdgcn_mfma_f32_16x16x32_bf16(a1, b1, acc[1][1], 0, 0, 0);
                acc[1][2] = __builtin_amdgcn_mfma_f32_16x16x32_bf16(a1, b2, acc[1][2], 0, 0, 0);
                acc[1][3] = __builtin_amdgcn_mfma_f32_16x16x32_bf16(a1, b3, acc[1][3], 0, 0, 0);
            }
        }
    }

    #pragma unroll
    for (int mt = 0; mt < 2; ++mt) {
        #pragma unroll
        for (int reg = 0; reg < 4; ++reg) {
            int pl = pbase + mt * 16 + (l >> 4) * 4 + reg;
            if (meta[pl * 4 + 1] >= 0) {
                int pt = meta[pl * 4 + 3];
                float* rp = &res[(long)pt * 64 + (l & 15)];
                #pragma unroll
                for (int ng = 0; ng < 4; ++ng) rp[ng * 16] = acc[mt][ng][reg];
            }
        }
    }
}

// ---------------- expand: compact res + idx map -> dense NCHW output (coalesced) ----------------
__global__ __launch_bounds__(256) void expand(const float4* __restrict__ res4,
                                              const int* __restrict__ idx,
                                              float* __restrict__ out) {
    const int y = blockIdx.x, b = blockIdx.y;
    const int tid = threadIdx.x;
    const long plane = (long)HH * WW;
    const int rbase = (b * HH + y) * WW;

    #pragma unroll
    for (int half = 0; half < 2; ++half) {
        int x = half * 256 + tid;
        if (x < WW) {
            int id = idx[rbase + x];
            long obase = (long)b * 64 * plane + (long)y * WW + x;
            #pragma unroll 4
            for (int c4 = 0; c4 < 16; ++c4) {
                float4 v = make_float4(0.f, 0.f, 0.f, 0.f);
                if (id >= 0) v = res4[(long)id * 16 + c4];
                out[obase + (c4 * 4 + 0) * plane] = v.x;
                out[obase + (c4 * 4 + 1) * plane] = v.y;
                out[obase + (c4 * 4 + 2) * plane] = v.z;
                out[obase + (c4 * 4 + 3) * plane] = v.w;
            }
        }
    }
}

extern "C" void kernel_launch(void* const* d_in, const int* in_sizes, int n_in,
                              void* d_out, int out_size, void* d_ws, size_t ws_size,
                              hipStream_t stream) {
    const float* feats = (const float*)d_in[0];
    const int* coors = (const int*)d_in[1];
    const float* W1 = (const float*)d_in[3];
    const float* W2 = (const float*)d_in[4];
    float* out = (float*)d_out;
    int npts = in_sizes[1] / 3;

    // d_ws layout:
    //   midB   MIDN ushorts
    //   zrowB  128 ushorts
    //   W1p    73728 ushorts
    //   W2p    73728 ushorts
    //   cnt    128 ints (counter g at cnt[g*32], 128B-padded)
    //   grp    4*npts ints
    //   idx    NIDX ints
    //   res    npts*64 floats
    //   featsB (npts+1)*64 ushorts (zero row at index npts)
    char* wsb = (char*)d_ws;
    unsigned short* midB  = (unsigned short*)wsb;
    unsigned short* zrowB = midB + MIDN;
    unsigned short* W1p   = zrowB + 128;
    unsigned short* W2p   = W1p + 73728;
    int* cnt = (int*)(W2p + 73728);
    int* grp = cnt + 128;
    int* idx = grp + 4 * npts;
    float* res = (float*)(idx + NIDX);
    unsigned short* featsB = (unsigned short*)(res + (size_t)npts * 64);

    // 1) fused prep
    int pthreads = (npts + 1) * 8;
    prep<<<(pthreads + 255) / 256, 256, 0, stream>>>(feats, W1, W2, featsB, W1p, W2p,
                                                     zrowB, cnt, idx, npts);

    // 2) classify: block-aggregated parity groups + pixel->point map
    classify<<<(npts + 255) / 256, 256, 0, stream>>>(coors, npts, grp, cnt, idx);

    // 3) conv1 via MFMA, 64j tile -> mid bf16
    conv1_mfma<<<dim3(3, HO, 4), 256, 0, stream>>>(featsB, idx, W1p, midB, npts);

    // 4) conv2 via MFMA -> compact res (indexed by original point id)
    int pblocks = (npts + 127) / 128;
    conv2_mfma<<<dim3(pblocks, 4), 256, 0, stream>>>(midB, W2p, coors, grp, cnt, res, npts);

    // 5) expand compact res to dense NCHW output (writes every element)
    expand<<<dim3(HH, 4), 256, 0, stream>>>((const float4*)res, idx, out);
}

// Round 17
// 104.643 us; speedup vs baseline: 2.6748x; 1.0554x over previous
//
#include <hip/hip_runtime.h>

#define HH 383
#define WW 383
#define CINC 64
#define COUTC 128
#define HO 191
#define WO 191
#define MIDN (4L * HO * WO * COUTC)   // 18,690,048 elements
#define NIDX (4 * HH * WW)            // 586,756 pixels

typedef __attribute__((ext_vector_type(8))) short short8;
typedef __attribute__((ext_vector_type(8))) unsigned short ushort8;
typedef __attribute__((ext_vector_type(4))) float f32x4;

static __device__ inline unsigned short f2bf(float f) {
    unsigned u = __float_as_uint(f);
    unsigned r = (u + 0x7FFFu + ((u >> 16) & 1u)) >> 16;
    return (unsigned short)r;
}

// ---------------- prep: pack W1/W2 frags, feats->bf16 compact, zero row, counters, idx=-1 ----------
__global__ void prep(const float* __restrict__ feats,
                     const float* __restrict__ W1, const float* __restrict__ W2,
                     unsigned short* __restrict__ featsB,
                     unsigned short* __restrict__ W1p, unsigned short* __restrict__ W2p,
                     unsigned short* __restrict__ zrow, int* __restrict__ cnt,
                     int* __restrict__ idx, int npts) {
    int t = blockIdx.x * blockDim.x + threadIdx.x;
    int N = gridDim.x * blockDim.x;
    if (t < 73728) {
        int j  = t & 7;
        int l  = (t >> 3) & 63;
        int ng = (t >> 9) & 7;
        int tk = t >> 12;
        int tap = tk >> 1, kc = tk & 1;
        int ci = kc * 32 + (l >> 4) * 8 + j;
        int co = ng * 16 + (l & 15);
        W1p[t] = f2bf(W1[(tap * 64 + ci) * 128 + co]);
        int ng2  = (t >> 9) & 3;
        int kc2  = (t >> 11) & 3;
        int tap2 = t >> 13;
        int m = kc2 * 32 + (l >> 4) * 8 + j;
        int c = ng2 * 16 + (l & 15);
        W2p[t] = f2bf(W2[(tap2 * 128 + m) * 64 + c]);
    }
    if (t < 128) zrow[t] = 0;
    if (t < 128) cnt[t] = 0;   // 4 counters at stride 32 ints (128 B)
    for (int i = t; i < NIDX; i += N) idx[i] = -1;
    if (t < (npts + 1) * 8) {
        int p = t >> 3, q = t & 7;
        ushort8 v = {0, 0, 0, 0, 0, 0, 0, 0};
        if (p < npts) {
            const float4* f4 = (const float4*)(feats + (long)p * 64 + q * 8);
            float4 a = f4[0], b = f4[1];
            v[0] = f2bf(a.x); v[1] = f2bf(a.y); v[2] = f2bf(a.z); v[3] = f2bf(a.w);
            v[4] = f2bf(b.x); v[5] = f2bf(b.y); v[6] = f2bf(b.z); v[7] = f2bf(b.w);
        }
        *(ushort8*)&featsB[(long)p * 64 + q * 8] = v;
    }
}

// ---------------- classify: block-aggregated parity grouping + pixel->point map ----------------
__global__ __launch_bounds__(256) void classify(const int* __restrict__ coors, int npts,
                                                int* __restrict__ grp, int* __restrict__ cnt,
                                                int* __restrict__ idx) {
    __shared__ int wcnt[4][4];
    __shared__ int bbase[4];
    int t = blockIdx.x * blockDim.x + threadIdx.x;
    int lane = threadIdx.x & 63, w = threadIdx.x >> 6;
    int g = -1;
    if (t < npts) {
        int b = coors[3 * t], y = coors[3 * t + 1], x = coors[3 * t + 2];
        g = (y & 1) * 2 + (x & 1);
        idx[(b * HH + y) * WW + x] = t;
    }
    int myrank = 0;
    #pragma unroll
    for (int gg = 0; gg < 4; ++gg) {
        unsigned long long mask = __ballot(g == gg);
        if (lane == 0) wcnt[w][gg] = __popcll(mask);
        if (g == gg) myrank = __popcll(mask & ((1ULL << lane) - 1ULL));
    }
    __syncthreads();
    if (threadIdx.x < 4) {
        int gg = threadIdx.x;
        int s0 = wcnt[0][gg], s1 = wcnt[1][gg], s2 = wcnt[2][gg], s3 = wcnt[3][gg];
        int tot = s0 + s1 + s2 + s3;
        bbase[gg] = tot ? atomicAdd(&cnt[gg * 32], tot) : 0;
        wcnt[0][gg] = 0;
        wcnt[1][gg] = s0;
        wcnt[2][gg] = s0 + s1;
        wcnt[3][gg] = s0 + s1 + s2;
    }
    __syncthreads();
    if (g >= 0)
        grp[g * npts + bbase[g] + wcnt[w][g] + myrank] = t;
}

// ---------------- conv1: 3x3 stride-2 VALID, bf16 MFMA, 64j-tile, kc-split staging ----------------
// block: 64 j x 128 co, 4 waves; wave w: co range [32w, 32w+32), ALL 64 j (4 m-tiles).
// K split: per kc-half (32 ch), stage 25.7 KB tile then 72 MFMA/wave. 5 blocks/CU occupancy.
// LDS layout: [r][h=xx>>1][slot*8ch], slot = ((xx&1)*4 + chunk) ^ (h&7)  -> 2-way reads (free).
__global__ __launch_bounds__(256, 5) void conv1_mfma(const unsigned short* __restrict__ featsB,
                                                     const int* __restrict__ idxm,
                                                     const unsigned short* __restrict__ W1p,
                                                     unsigned short* __restrict__ mid, int npts) {
    __shared__ unsigned short lds[3 * 67 * 64];   // 25,728 B
    __shared__ int ids[400];
    const int j0 = blockIdx.x * 64;
    const int i  = blockIdx.y;
    const int b  = blockIdx.z;
    const int tid = threadIdx.x;
    const int w = tid >> 6, l = tid & 63;

    // phase A: one idx lookup per pixel (rows 2i..2i+2, x = 2*j0 .. 2*j0+128)
    for (int t = tid; t < 396; t += 256) {
        int r = t / 132, xx = t - r * 132;
        int gx = 2 * j0 + xx;
        int id = npts;
        if (gx < WW) {
            int v = idxm[(b * HH + 2 * i + r) * WW + gx];
            if (v >= 0) id = v;
        }
        ids[t] = id;
    }

    const int pj0 = l & 15;
    const int q8 = l >> 4;            // chunk within staged 32ch
    f32x4 zf = {0.f, 0.f, 0.f, 0.f};
    f32x4 acc[4][2];
    #pragma unroll
    for (int mt = 0; mt < 4; ++mt) { acc[mt][0] = zf; acc[mt][1] = zf; }

    for (int kc = 0; kc < 2; ++kc) {
        __syncthreads();   // ids ready (kc=0) / previous MFMA readers done (kc=1)
        // stage 32 channels: 396 pixels x 4 chunks of 8ch
        for (int t = tid; t < 1584; t += 256) {
            int pix = t >> 2, c4v = t & 3;
            int r = pix / 132, xx = pix - r * 132;
            int h = xx >> 1, par = xx & 1;
            ushort8 v = *(const ushort8*)&featsB[(long)ids[pix] * 64 + kc * 32 + c4v * 8];
            int slot = (par * 4 + c4v) ^ (h & 7);
            *(ushort8*)&lds[(r * 67 + h) * 64 + slot * 8] = v;
        }
        __syncthreads();

        for (int ky = 0; ky < 3; ++ky) {
            for (int kx = 0; kx < 3; ++kx) {
                const int tap = ky * 3 + kx;
                int fo = (((tap * 2 + kc) * 8 + 2 * w) << 9) + l * 8;
                short8 b0 = *(const short8*)&W1p[fo];
                short8 b1 = *(const short8*)&W1p[fo + 512];
                const int par = kx & 1, kh = kx >> 1;
                #pragma unroll
                for (int mt = 0; mt < 4; ++mt) {
                    int h = pj0 + mt * 16 + kh;
                    int slot = (par * 4 + q8) ^ (h & 7);
                    short8 a = *(const short8*)&lds[(ky * 67 + h) * 64 + slot * 8];
                    acc[mt][0] = __builtin_amdgcn_mfma_f32_16x16x32_bf16(a, b0, acc[mt][0], 0, 0, 0);
                    acc[mt][1] = __builtin_amdgcn_mfma_f32_16x16x32_bf16(a, b1, acc[mt][1], 0, 0, 0);
                }
            }
        }
    }

    // epilogue: D col = l&15 -> co, row = (l>>4)*4+reg -> j (m89-verified layout)
    const int n0 = 32 * w + (l & 15);
    const int rowbase = (l >> 4) * 4;
    #pragma unroll
    for (int mt = 0; mt < 4; ++mt) {
        #pragma unroll
        for (int reg = 0; reg < 4; ++reg) {
            int j = j0 + mt * 16 + rowbase + reg;
            if (j < WO) {
                long base = (((long)b * HO + i) * WO + j) * COUTC;
                mid[base + n0]      = f2bf(acc[mt][0][reg]);
                mid[base + n0 + 16] = f2bf(acc[mt][1][reg]);
            }
        }
    }
}

// ---------------- conv2: parity-grouped masked deconv via bf16 MFMA gather-GEMM ----------------
__global__ __launch_bounds__(256, 4) void conv2_mfma(const unsigned short* __restrict__ mid,
                                                     const unsigned short* __restrict__ W2p,
                                                     const int* __restrict__ coors,
                                                     const int* __restrict__ grp,
                                                     const int* __restrict__ cnt,
                                                     float* __restrict__ res, int npts) {
    __shared__ int meta[128 * 4];

    const int g  = blockIdx.y;
    const int n  = cnt[g * 32];
    const int p0 = blockIdx.x * 128;
    if (p0 >= n) return;
    const int gy = g >> 1, gx = g & 1;
    const int tid = threadIdx.x, l = tid & 63, w = tid >> 6;

    if (tid < 128) {
        int pp = p0 + tid;
        if (pp < n) {
            int t = grp[g * npts + pp];
            meta[tid * 4 + 0] = coors[3 * t + 0];
            meta[tid * 4 + 1] = coors[3 * t + 1];
            meta[tid * 4 + 2] = coors[3 * t + 2];
            meta[tid * 4 + 3] = t;
        } else {
            meta[tid * 4 + 1] = -1;
        }
    }
    __syncthreads();

    const int pbase = w * 32;
    const int hi8 = (l >> 4) * 8;
    int bA[2], yA[2], xA[2];
    #pragma unroll
    for (int mt = 0; mt < 2; ++mt) {
        int pA = pbase + mt * 16 + (l & 15);
        bA[mt] = meta[pA * 4 + 0];
        yA[mt] = meta[pA * 4 + 1];
        xA[mt] = meta[pA * 4 + 2];
    }

    f32x4 zf = {0.f, 0.f, 0.f, 0.f};
    f32x4 acc[2][4];
    #pragma unroll
    for (int mt = 0; mt < 2; ++mt)
        #pragma unroll
        for (int ng = 0; ng < 4; ++ng) acc[mt][ng] = zf;

    const int nsy = gy ? 1 : 2, nsx = gx ? 1 : 2;
    for (int sy = 0; sy < nsy; ++sy) {
        const int ky = gy ? 1 : sy * 2;
        for (int sx = 0; sx < nsx; ++sx) {
            const int kx = gx ? 1 : sx * 2;
            const int tap = ky * 3 + kx;
            long off[2];
            #pragma unroll
            for (int mt = 0; mt < 2; ++mt) {
                int i = gy ? (yA[mt] >> 1) : ((yA[mt] >> 1) - 1 + sy);
                int j = gx ? (xA[mt] >> 1) : ((xA[mt] >> 1) - 1 + sx);
                bool ok = (yA[mt] >= 0) && (unsigned)i < (unsigned)HO && (unsigned)j < (unsigned)WO;
                off[mt] = ok ? ((long)(bA[mt] * HO + i) * WO + j) * COUTC : MIDN;
            }

            #pragma unroll
            for (int kc = 0; kc < 4; ++kc) {
                short8 a0 = *(const short8*)&mid[off[0] + kc * 32 + hi8];
                short8 a1 = *(const short8*)&mid[off[1] + kc * 32 + hi8];
                const unsigned short* wp = &W2p[((tap * 4 + kc) * 4) * 512 + l * 8];
                short8 b0 = *(const short8*)&wp[0];
                short8 b1 = *(const short8*)&wp[512];
                short8 b2 = *(const short8*)&wp[1024];
                short8 b3 = *(const short8*)&wp[1536];
                acc[0][0] = __builtin_amdgcn_mfma_f32_16x16x32_bf16(a0, b0, acc[0][0], 0, 0, 0);
                acc[0][1] = __builtin_amdgcn_mfma_f32_16x16x32_bf16(a0, b1, acc[0][1], 0, 0, 0);
                acc[0][2] = __builtin_amdgcn_mfma_f32_16x16x32_bf16(a0, b2, acc[0][2], 0, 0, 0);
                acc[0][3] = __builtin_amdgcn_mfma_f32_16x16x32_bf16(a0, b3, acc[0][3], 0, 0, 0);
                acc[1][0] = __builtin_amdgcn_mfma_f32_16x16x32_bf16(a1, b0, acc[1][0], 0, 0, 0);
                acc[1][1] = __builtin_amdgcn_mfma_f32_16x16x32_bf16(a1, b1, acc[1][1], 0, 0, 0);
                acc[1][2] = __builtin_amdgcn_mfma_f32_16x16x32_bf16(a1, b2, acc[1][2], 0, 0, 0);
                acc[1][3] = __builtin_amdgcn_mfma_f32_16x16x32_bf16(a1, b3, acc[1][3], 0, 0, 0);
            }
        }
    }

    #pragma unroll
    for (int mt = 0; mt < 2; ++mt) {
        #pragma unroll
        for (int reg = 0; reg < 4; ++reg) {
            int pl = pbase + mt * 16 + (l >> 4) * 4 + reg;
            if (meta[pl * 4 + 1] >= 0) {
                int pt = meta[pl * 4 + 3];
                float* rp = &res[(long)pt * 64 + (l & 15)];
                #pragma unroll
                for (int ng = 0; ng < 4; ++ng) rp[ng * 16] = acc[mt][ng][reg];
            }
        }
    }
}

// ---------------- expand: compact res + idx map -> dense NCHW output (coalesced) ----------------
__global__ __launch_bounds__(256) void expand(const float4* __restrict__ res4,
                                              const int* __restrict__ idx,
                                              float* __restrict__ out) {
    const int y = blockIdx.x, b = blockIdx.y;
    const int tid = threadIdx.x;
    const long plane = (long)HH * WW;
    const int rbase = (b * HH + y) * WW;

    #pragma unroll
    for (int half = 0; half < 2; ++half) {
        int x = half * 256 + tid;
        if (x < WW) {
            int id = idx[rbase + x];
            long obase = (long)b * 64 * plane + (long)y * WW + x;
            #pragma unroll 4
            for (int c4 = 0; c4 < 16; ++c4) {
                float4 v = make_float4(0.f, 0.f, 0.f, 0.f);
                if (id >= 0) v = res4[(long)id * 16 + c4];
                out[obase + (c4 * 4 + 0) * plane] = v.x;
                out[obase + (c4 * 4 + 1) * plane] = v.y;
                out[obase + (c4 * 4 + 2) * plane] = v.z;
                out[obase + (c4 * 4 + 3) * plane] = v.w;
            }
        }
    }
}

extern "C" void kernel_launch(void* const* d_in, const int* in_sizes, int n_in,
                              void* d_out, int out_size, void* d_ws, size_t ws_size,
                              hipStream_t stream) {
    const float* feats = (const float*)d_in[0];
    const int* coors = (const int*)d_in[1];
    const float* W1 = (const float*)d_in[3];
    const float* W2 = (const float*)d_in[4];
    float* out = (float*)d_out;
    int npts = in_sizes[1] / 3;

    char* wsb = (char*)d_ws;
    unsigned short* midB  = (unsigned short*)wsb;
    unsigned short* zrowB = midB + MIDN;
    unsigned short* W1p   = zrowB + 128;
    unsigned short* W2p   = W1p + 73728;
    int* cnt = (int*)(W2p + 73728);
    int* grp = cnt + 128;
    int* idx = grp + 4 * npts;
    float* res = (float*)(idx + NIDX);
    unsigned short* featsB = (unsigned short*)(res + (size_t)npts * 64);

    // 1) fused prep
    int pthreads = (npts + 1) * 8;
    prep<<<(pthreads + 255) / 256, 256, 0, stream>>>(feats, W1, W2, featsB, W1p, W2p,
                                                     zrowB, cnt, idx, npts);

    // 2) classify: block-aggregated parity groups + pixel->point map
    classify<<<(npts + 255) / 256, 256, 0, stream>>>(coors, npts, grp, cnt, idx);

    // 3) conv1 via MFMA, 64j tile, kc-split staging (5 blocks/CU) -> mid bf16
    conv1_mfma<<<dim3(3, HO, 4), 256, 0, stream>>>(featsB, idx, W1p, midB, npts);

    // 4) conv2 via MFMA -> compact res (indexed by original point id)
    int pblocks = (npts + 127) / 128;
    conv2_mfma<<<dim3(pblocks, 4), 256, 0, stream>>>(midB, W2p, coors, grp, cnt, res, npts);

    // 5) expand compact res to dense NCHW output (writes every element)
    expand<<<dim3(HH, 4), 256, 0, stream>>>((const float4*)res, idx, out);
}